// Round 7
// baseline (9042.532 us; speedup 1.0000x reference)
//
#include <hip/hip_runtime.h>
#include <stdint.h>

#define B_ 32
#define T_ 512
#define E_ 1024
#define H_ 1024
#define NBLK 16    // k_rnn: 16 blocks x 4 compute waves; unit w owns cols [16w,16w+16)

typedef __attribute__((ext_vector_type(8))) short short8;
typedef __attribute__((ext_vector_type(4))) float floatx4;
typedef __attribute__((ext_vector_type(4))) int int4v;
typedef unsigned long long ull;

union U16 { ull u[2]; short8 s; int4v v; };

__device__ __forceinline__ unsigned short bf16_of(float f) {
    unsigned u = __float_as_uint(f);
    return (unsigned short)((u + 0x8000u) >> 16);   // round-half-up to bf16
}

__device__ __forceinline__ short8 load_bf8(const float* __restrict__ p) {
    const float4* q = (const float4*)p;
    float4 v0 = q[0];
    float4 v1 = q[1];
    short8 r;
    r[0] = (short)bf16_of(v0.x); r[1] = (short)bf16_of(v0.y);
    r[2] = (short)bf16_of(v0.z); r[3] = (short)bf16_of(v0.w);
    r[4] = (short)bf16_of(v1.x); r[5] = (short)bf16_of(v1.y);
    r[6] = (short)bf16_of(v1.z); r[7] = (short)bf16_of(v1.w);
    return r;
}

// ---------------------------------------------------------------------------
// K1: xp[n,h] = sum_e x[n,e] * Wih[h,e] + (bih[h]+bhh[h])   (unchanged)
// ---------------------------------------------------------------------------
__global__ __launch_bounds__(256) void k_xp(const float* __restrict__ x,
                                            const float* __restrict__ Wih,
                                            const float* __restrict__ bih,
                                            const float* __restrict__ bhh,
                                            float* __restrict__ out) {
    const int tid  = threadIdx.x;
    const int w    = tid >> 6;
    const int lane = tid & 63;
    const int l15  = lane & 15;
    const int quad = lane >> 4;
    const int rb = blockIdx.x >> 3;      // 128 row-blocks of 128 rows
    const int cb = blockIdx.x & 7;       // 8 col-blocks of 128 cols
    const int row_base = rb * 128 + w * 32;
    const int col_base = cb * 128;

    floatx4 acc[2][8];
#pragma unroll
    for (int i = 0; i < 2; i++)
#pragma unroll
        for (int j = 0; j < 8; j++) acc[i][j] = (floatx4)0.0f;

    for (int k0 = 0; k0 < E_; k0 += 32) {
        const int koff = k0 + quad * 8;
        short8 a[2];
#pragma unroll
        for (int mt = 0; mt < 2; mt++)
            a[mt] = load_bf8(x + (size_t)(row_base + mt * 16 + l15) * E_ + koff);
        short8 b[8];
#pragma unroll
        for (int nt = 0; nt < 8; nt++)
            b[nt] = load_bf8(Wih + (size_t)(col_base + nt * 16 + l15) * E_ + koff);
#pragma unroll
        for (int mt = 0; mt < 2; mt++)
#pragma unroll
            for (int nt = 0; nt < 8; nt++)
                acc[mt][nt] = __builtin_amdgcn_mfma_f32_16x16x32_bf16(
                    a[mt], b[nt], acc[mt][nt], 0, 0, 0);
    }

#pragma unroll
    for (int nt = 0; nt < 8; nt++) {
        const int col = col_base + nt * 16 + l15;
        const float bias = bih[col] + bhh[col];
#pragma unroll
        for (int mt = 0; mt < 2; mt++) {
            const int row = row_base + mt * 16 + quad * 4;
#pragma unroll
            for (int r = 0; r < 4; r++)
                out[(size_t)(row + r) * H_ + col] = acc[mt][nt][r] + bias;
        }
    }
}

// ---------------------------------------------------------------------------
// ws layout (u32 units): [0,1024) flag region; flag(b) = ws[b*16]
// (16 flags, 64B stride). Ring slots at 1024 + s*16384, each 64KB blocked
// bf16 (lo 32KB / hi 32KB). Slot ring-1 holds h_{-1} = 0.
// ---------------------------------------------------------------------------
__global__ void k_init(unsigned* __restrict__ ws, int ring) {
    const int i = blockIdx.x * blockDim.x + threadIdx.x;   // 0..16383
    if (i < 1024) ws[i] = 0u;
    ws[1024 + (ring - 1) * 16384 + i] = 0u;
}

// ---------------------------------------------------------------------------
// K3 v10b: v6's proven protocol, 4x fewer participants.
// 16 blocks x 384 threads: waves 0..3 = compute (each is v6's wave0 for its
// own 16 columns, wid = bid*4+wv; ring layout/addressing byte-identical to
// v6), waves 4..5 = service (xp prefetch + out writeback for all 64 block
// columns). One flag per BLOCK: published by wave0/lane0 AFTER the step
// barrier, which orders it behind all four compute waves' vmcnt(0)-acked
// agent stores (same safety argument as v6's per-wave flag). The per-step
// global barrier is now a 16-way flag exchange (max-of-16 tail, 4x less
// MALL poll traffic) instead of 64-way.
// Read path identical to v6: plain ring loads (L1/L2 amplified — the four
// compute waves of a block share one slot read) + agent acquire fence every
// `ring` steps. v9's direct-MALL reads are reverted (measured -59%).
// v10b fix: nontemporal stores use ext-vector floatx4 (HIP float4 is a
// class type the builtin rejects — round 6 compile error).
// ---------------------------------------------------------------------------
__global__ __launch_bounds__(384, 1) void k_rnn(const float* __restrict__ Whh,
                                                float* __restrict__ out,
                                                unsigned* __restrict__ ws,
                                                int ring) {
    const int tid  = threadIdx.x;
    const int wv   = tid >> 6;        // 0..3 compute, 4..5 service
    const int lane = tid & 63;
    const int bid  = blockIdx.x;      // 0..15

    unsigned* flags = ws;             // 16 flags, 64B stride

    __shared__ unsigned short sh_h[4 * 512];   // per-wave transpose regions
    __shared__ float sh_hf[2][2048];           // h fp32 handoff comp->svc
    __shared__ float sh_xp[2][2048];           // xp staging svc->comp

    if (wv < 4) {
        const int wid  = bid * 4 + wv;        // 0..63, v6 unit id
        const int j0   = wid * 16;
        const int l15  = lane & 15;
        const int quad = lane >> 4;
        const int mt_s = lane >> 5;
        const int sub  = (lane >> 4) & 1;
        const int m_s  = lane & 15;
        const int slot = (wid >> 1) * 128 + mt_s * 64 + (wid & 1) * 32 + sub * 16 + m_s;
        const int lds_off = wv * 1024 + mt_s * 512 + m_s * 32 + sub * 16; // bytes

        // Full-K W_hh B-fragments (128 VGPRs).
        short8 wreg[32];
#pragma unroll
        for (int c = 0; c < 32; c++)
            wreg[c] = load_bf8(Whh + (size_t)(j0 + l15) * H_ + c * 32 + quad * 8);

        __syncthreads();   // prologue: service filled sh_xp[0]

#pragma unroll 1
        for (int t = 0; t < T_; t++) {
            const int rs  = (t + ring - 1) & (ring - 1);
            const int wsl = t & (ring - 1);
            const ull* hA = (const ull*)(ws + 1024 + rs * 16384);
            const ull* hB = hA + 4096;
            ull* nxA = (ull*)(ws + 1024 + wsl * 16384);
            ull* nxB = nxA + 4096;

            if (t > 0) {
                const unsigned tv = (unsigned)t;
                while (true) {
                    unsigned v = __hip_atomic_load(&flags[(lane & 15) * 16],
                                                   __ATOMIC_RELAXED,
                                                   __HIP_MEMORY_SCOPE_AGENT);
                    if (__ballot(v < tv) == 0ull) break;
                }
                if ((t & (ring - 1)) == 0)
                    __builtin_amdgcn_fence(__ATOMIC_ACQUIRE, "agent");
                else
                    asm volatile("" ::: "memory");
            }

            floatx4 acc[2];
            acc[0] = (floatx4)0.0f;
            acc[1] = (floatx4)0.0f;
#pragma unroll
            for (int c = 0; c < 32; c++) {
#pragma unroll
                for (int mt = 0; mt < 2; mt++) {
                    U16 u;
                    u.u[0] = hA[(c * 2 + mt) * 64 + lane];
                    u.u[1] = hB[(c * 2 + mt) * 64 + lane];
                    acc[mt] = __builtin_amdgcn_mfma_f32_16x16x32_bf16(
                        u.s, wreg[c], acc[mt], 0, 0, 0);
                }
            }

            // xp from LDS (staged by service at iteration t-1), tanh, handoffs.
#pragma unroll
            for (int mt = 0; mt < 2; mt++)
#pragma unroll
                for (int r = 0; r < 4; r++) {
                    const int b = mt * 16 + quad * 4 + r;
                    const float p = sh_xp[t & 1][b * 64 + wv * 16 + l15] + acc[mt][r];
                    const float h = 1.0f - 2.0f / (__expf(2.0f * p) + 1.0f);
                    sh_hf[t & 1][b * 64 + wv * 16 + l15] = h;     // -> service
                    sh_h[wv * 512 + b * 16 + l15] = bf16_of(h);   // -> transpose
                }

            // In-wave DS ordering: reads below see the writes above.
            U16 pk;
            pk.v = *(const int4v*)((const char*)sh_h + lds_off);
            __hip_atomic_store(nxA + slot, pk.u[0], __ATOMIC_RELAXED,
                               __HIP_MEMORY_SCOPE_AGENT);
            __hip_atomic_store(nxB + slot, pk.u[1], __ATOMIC_RELAXED,
                               __HIP_MEMORY_SCOPE_AGENT);

            asm volatile("s_waitcnt vmcnt(0)" ::: "memory");  // 2 MALL acks only

            __syncthreads();   // step barrier: all 4 waves' stores acked

            if (wv == 0 && lane == 0)
                __hip_atomic_store(&flags[bid * 16], (unsigned)(t + 1),
                                   __ATOMIC_RELAXED, __HIP_MEMORY_SCOPE_AGENT);
        }
    } else {
        // ---- service waves: xp prefetch + fp32 out writeback (128 lanes) ----
        const int svl = tid - 256;          // 0..127
        const int b   = svl >> 2;           // batch 0..31
        const int cs  = (svl & 3) * 16;     // col offset 0/16/32/48
        const float* xp_base  = out + (size_t)b * T_ * H_ + bid * 64 + cs;
        float*       out_base = out + (size_t)b * T_ * H_ + bid * 64 + cs;

        // prologue: stage xp(0) -> sh_xp[0]
#pragma unroll
        for (int k = 0; k < 4; k++)
            *(floatx4*)&sh_xp[0][b * 64 + cs + 4 * k] =
                *(const floatx4*)(xp_base + 4 * k);
        __syncthreads();

        floatx4 hold[4];
#pragma unroll 1
        for (int t = 0; t < T_; t++) {
            // xp loads for t+1 first (HBM latency overlaps compute waves).
            floatx4 v[4];
            const bool more = (t + 1 < T_);
            if (more) {
#pragma unroll
                for (int k = 0; k < 4; k++)
                    v[k] = *(const floatx4*)(xp_base + (size_t)(t + 1) * H_ + 4 * k);
            }
            // out stores for step t-1 (fire-and-forget; acks stall svc only)
            if (t > 0) {
#pragma unroll
                for (int k = 0; k < 4; k++)
                    __builtin_nontemporal_store(
                        hold[k], (floatx4*)(out_base + (size_t)(t - 1) * H_ + 4 * k));
            }
            if (more) {
#pragma unroll
                for (int k = 0; k < 4; k++)
                    *(floatx4*)&sh_xp[(t + 1) & 1][b * 64 + cs + 4 * k] = v[k];
            }
            __syncthreads();   // step barrier: sh_hf[t&1] now valid
#pragma unroll
            for (int k = 0; k < 4; k++)
                hold[k] = *(const floatx4*)&sh_hf[t & 1][b * 64 + cs + 4 * k];
        }
        // epilogue: out for step T-1
#pragma unroll
        for (int k = 0; k < 4; k++)
            __builtin_nontemporal_store(
                hold[k], (floatx4*)(out_base + (size_t)(T_ - 1) * H_ + 4 * k));
    }
}

// ---------------------------------------------------------------------------
extern "C" void kernel_launch(void* const* d_in, const int* in_sizes, int n_in,
                              void* d_out, int out_size, void* d_ws, size_t ws_size,
                              hipStream_t stream) {
    const float* x   = (const float*)d_in[0];
    const float* Wih = (const float*)d_in[1];
    const float* Whh = (const float*)d_in[2];
    const float* bih = (const float*)d_in[3];
    const float* bhh = (const float*)d_in[4];
    float* out = (float*)d_out;
    unsigned* ws = (unsigned*)d_ws;

    // ring=8 needs 4KB flags + 8*64KB; fallback ring=2 fits 132KB.
    const size_t need8 = (size_t)(1024 + 8 * 16384) * sizeof(unsigned);
    const int ring = (ws_size >= need8) ? 8 : 2;

    k_init<<<64, 256, 0, stream>>>(ws, ring);
    k_xp<<<128 * 8, 256, 0, stream>>>(x, Wih, bih, bhh, out);
    k_rnn<<<NBLK, 384, 0, stream>>>(Whh, out, ws, ring);
}

// Round 8
// 3322.025 us; speedup vs baseline: 2.7220x; 2.7220x over previous
//
#include <hip/hip_runtime.h>
#include <stdint.h>

#define B_ 32
#define T_ 512
#define E_ 1024
#define H_ 1024
#define NWAVE 64   // k_rnn: 64 blocks; wave j owns h-cols [16j,16j+16)

typedef __attribute__((ext_vector_type(8))) short short8;
typedef __attribute__((ext_vector_type(4))) float floatx4;
typedef __attribute__((ext_vector_type(4))) int int4v;
typedef unsigned long long ull;

union U16 { ull u[2]; short8 s; int4v v; };

__device__ __forceinline__ unsigned short bf16_of(float f) {
    unsigned u = __float_as_uint(f);
    return (unsigned short)((u + 0x8000u) >> 16);   // round-half-up to bf16
}

__device__ __forceinline__ short8 load_bf8(const float* __restrict__ p) {
    const float4* q = (const float4*)p;
    float4 v0 = q[0];
    float4 v1 = q[1];
    short8 r;
    r[0] = (short)bf16_of(v0.x); r[1] = (short)bf16_of(v0.y);
    r[2] = (short)bf16_of(v0.z); r[3] = (short)bf16_of(v0.w);
    r[4] = (short)bf16_of(v1.x); r[5] = (short)bf16_of(v1.y);
    r[6] = (short)bf16_of(v1.z); r[7] = (short)bf16_of(v1.w);
    return r;
}

// ---------------------------------------------------------------------------
// K1: xp[n,h] = sum_e x[n,e] * Wih[h,e] + (bih[h]+bhh[h])   (unchanged)
// ---------------------------------------------------------------------------
__global__ __launch_bounds__(256) void k_xp(const float* __restrict__ x,
                                            const float* __restrict__ Wih,
                                            const float* __restrict__ bih,
                                            const float* __restrict__ bhh,
                                            float* __restrict__ out) {
    const int tid  = threadIdx.x;
    const int w    = tid >> 6;
    const int lane = tid & 63;
    const int l15  = lane & 15;
    const int quad = lane >> 4;
    const int rb = blockIdx.x >> 3;      // 128 row-blocks of 128 rows
    const int cb = blockIdx.x & 7;       // 8 col-blocks of 128 cols
    const int row_base = rb * 128 + w * 32;
    const int col_base = cb * 128;

    floatx4 acc[2][8];
#pragma unroll
    for (int i = 0; i < 2; i++)
#pragma unroll
        for (int j = 0; j < 8; j++) acc[i][j] = (floatx4)0.0f;

    for (int k0 = 0; k0 < E_; k0 += 32) {
        const int koff = k0 + quad * 8;
        short8 a[2];
#pragma unroll
        for (int mt = 0; mt < 2; mt++)
            a[mt] = load_bf8(x + (size_t)(row_base + mt * 16 + l15) * E_ + koff);
        short8 b[8];
#pragma unroll
        for (int nt = 0; nt < 8; nt++)
            b[nt] = load_bf8(Wih + (size_t)(col_base + nt * 16 + l15) * E_ + koff);
#pragma unroll
        for (int mt = 0; mt < 2; mt++)
#pragma unroll
            for (int nt = 0; nt < 8; nt++)
                acc[mt][nt] = __builtin_amdgcn_mfma_f32_16x16x32_bf16(
                    a[mt], b[nt], acc[mt][nt], 0, 0, 0);
    }

#pragma unroll
    for (int nt = 0; nt < 8; nt++) {
        const int col = col_base + nt * 16 + l15;
        const float bias = bih[col] + bhh[col];
#pragma unroll
        for (int mt = 0; mt < 2; mt++) {
            const int row = row_base + mt * 16 + quad * 4;
#pragma unroll
            for (int r = 0; r < 4; r++)
                out[(size_t)(row + r) * H_ + col] = acc[mt][nt][r] + bias;
        }
    }
}

// ---------------------------------------------------------------------------
// ws layout (u32 units): flags at ws[0..63] — 4B stride, 64 flags packed
// into FOUR 64B lines (v11's single change vs v6: a wave's poll is one
// coalesced 4-line load = 256 MALL transactions/round instead of 4096).
// Ring slots at 1024 + s*16384, each 64KB blocked bf16 (lo 32KB / hi 32KB).
// Slot ring-1 holds h_{-1} = 0.
// ---------------------------------------------------------------------------
__global__ void k_init(unsigned* __restrict__ ws, int ring) {
    const int i = blockIdx.x * blockDim.x + threadIdx.x;   // 0..16383
    if (i < 1024) ws[i] = 0u;
    ws[1024 + (ring - 1) * 16384 + i] = 0u;
}

// ---------------------------------------------------------------------------
// K3 v11 = v6 byte-identical (64 blocks x 128 threads, wave0 compute /
// wave1 service, 176-VGPR codegen with wreg register-resident — v10b's
// 4x regression was the 384-thread shape capping VGPR at 128 and spilling
// wreg) EXCEPT the flag layout: packed 4B stride.
//   - poll: flags[lane] (4 lines; correctness proven by v9 which used the
//     identical packed poll and passed).
//   - publish: flags[wid] after vmcnt(0)-acked agent h-stores (v6 order).
//   - read path: plain ring loads + agent acquire fence every `ring` steps
//     (v6 exact; v9's system-scope reads were the -59% and are NOT here).
// ---------------------------------------------------------------------------
__global__ __launch_bounds__(128, 1) void k_rnn(const float* __restrict__ Whh,
                                                float* __restrict__ out,
                                                unsigned* __restrict__ ws,
                                                int ring) {
    const int tid  = threadIdx.x;
    const int wv   = tid >> 6;        // 0 = sync/compute, 1 = service
    const int lane = tid & 63;
    const int wid  = blockIdx.x;      // 0..63
    const int j0   = wid * 16;

    unsigned* flags = ws;             // 64 flags, 4B stride (4 cache lines)

    __shared__ unsigned short sh_h[512];   // A-layout transpose (wave0 private)
    __shared__ float sh_hf[2][512];        // h fp32 handoff w0->w1 [parity][b*16+col]
    __shared__ float sh_xp[2][512];        // xp staging w1->w0 [parity][b*16+col]

    if (wv == 0) {
        const int l15  = lane & 15;
        const int quad = lane >> 4;
        const int mt_s = lane >> 5;
        const int sub  = (lane >> 4) & 1;
        const int m_s  = lane & 15;
        const int slot = (wid >> 1) * 128 + mt_s * 64 + (wid & 1) * 32 + sub * 16 + m_s;
        const int lds_off = mt_s * 512 + m_s * 32 + sub * 16;   // bytes into sh_h

        // Full-K W_hh B-fragments (128 VGPRs).
        short8 wreg[32];
#pragma unroll
        for (int c = 0; c < 32; c++)
            wreg[c] = load_bf8(Whh + (size_t)(j0 + l15) * H_ + c * 32 + quad * 8);

        __syncthreads();   // prologue: wave1 filled sh_xp[0]

#pragma unroll 1
        for (int t = 0; t < T_; t++) {
            const int rs  = (t + ring - 1) & (ring - 1);
            const int wsl = t & (ring - 1);
            const ull* hA = (const ull*)(ws + 1024 + rs * 16384);
            const ull* hB = hA + 4096;
            ull* nxA = (ull*)(ws + 1024 + wsl * 16384);
            ull* nxB = nxA + 4096;

            if (t > 0) {
                const unsigned tv = (unsigned)t;
                while (true) {
                    unsigned v = __hip_atomic_load(&flags[lane],
                                                   __ATOMIC_RELAXED,
                                                   __HIP_MEMORY_SCOPE_AGENT);
                    if (__ballot(v < tv) == 0ull) break;
                }
                if ((t & (ring - 1)) == 0)
                    __builtin_amdgcn_fence(__ATOMIC_ACQUIRE, "agent");
                else
                    asm volatile("" ::: "memory");
            }

            floatx4 acc[2];
            acc[0] = (floatx4)0.0f;
            acc[1] = (floatx4)0.0f;
#pragma unroll
            for (int c = 0; c < 32; c++) {
#pragma unroll
                for (int mt = 0; mt < 2; mt++) {
                    U16 u;
                    u.u[0] = hA[(c * 2 + mt) * 64 + lane];
                    u.u[1] = hB[(c * 2 + mt) * 64 + lane];
                    acc[mt] = __builtin_amdgcn_mfma_f32_16x16x32_bf16(
                        u.s, wreg[c], acc[mt], 0, 0, 0);
                }
            }

            // xp from LDS (staged by wave1 at iteration t-1), tanh, handoffs.
#pragma unroll
            for (int mt = 0; mt < 2; mt++)
#pragma unroll
                for (int r = 0; r < 4; r++) {
                    const int b = mt * 16 + quad * 4 + r;
                    const float p = sh_xp[t & 1][b * 16 + l15] + acc[mt][r];
                    const float h = 1.0f - 2.0f / (__expf(2.0f * p) + 1.0f);
                    sh_hf[t & 1][b * 16 + l15] = h;          // -> wave1 (out)
                    sh_h[b * 16 + l15] = bf16_of(h);         // -> transpose
                }

            // In-wave DS ordering: reads below see the writes above.
            U16 pk;
            pk.v = *(const int4v*)((const char*)sh_h + lds_off);
            __hip_atomic_store(nxA + slot, pk.u[0], __ATOMIC_RELAXED,
                               __HIP_MEMORY_SCOPE_AGENT);
            __hip_atomic_store(nxB + slot, pk.u[1], __ATOMIC_RELAXED,
                               __HIP_MEMORY_SCOPE_AGENT);

            asm volatile("s_waitcnt vmcnt(0)" ::: "memory");  // 2 MALL acks only
            if (lane == 0)
                __hip_atomic_store(&flags[wid], (unsigned)(t + 1),
                                   __ATOMIC_RELAXED, __HIP_MEMORY_SCOPE_AGENT);

            __syncthreads();   // step barrier (wave1 handoff)
        }
    } else {
        // ---- service wave: xp prefetch + fp32 out writeback ----
        const int b  = lane >> 1;           // batch 0..31
        const int cs = (lane & 1) * 8;      // col offset 0 or 8
        const float* xp_base = out + (size_t)b * T_ * H_ + j0 + cs;
        float*       out_base = out + (size_t)b * T_ * H_ + j0 + cs;

        // prologue: stage xp(0) -> sh_xp[0]
        {
            float4 v0 = *(const float4*)(xp_base + 0);
            float4 v1 = *(const float4*)(xp_base + 4);
            *(float4*)&sh_xp[0][b * 16 + cs]     = v0;
            *(float4*)&sh_xp[0][b * 16 + cs + 4] = v1;
        }
        __syncthreads();

        float hold[8];
#pragma unroll 1
        for (int t = 0; t < T_; t++) {
            // xp loads for t+1 first (so the ds_write wait targets them).
            float4 v0, v1;
            const bool more = (t + 1 < T_);
            if (more) {
                v0 = *(const float4*)(xp_base + (size_t)(t + 1) * H_);
                v1 = *(const float4*)(xp_base + (size_t)(t + 1) * H_ + 4);
            }
            // out stores for step t-1 (fire-and-forget; acks stall wave1 only)
            if (t > 0) {
#pragma unroll
                for (int k = 0; k < 8; k++)
                    __builtin_nontemporal_store(
                        hold[k], out_base + (size_t)(t - 1) * H_ + k);
            }
            if (more) {
                *(float4*)&sh_xp[(t + 1) & 1][b * 16 + cs]     = v0;
                *(float4*)&sh_xp[(t + 1) & 1][b * 16 + cs + 4] = v1;
            }
            __syncthreads();   // step barrier: wave0's sh_hf[t&1] now valid
#pragma unroll
            for (int k = 0; k < 8; k++)
                hold[k] = sh_hf[t & 1][b * 16 + cs + k];
        }
        // epilogue: out for step T-1
#pragma unroll
        for (int k = 0; k < 8; k++)
            __builtin_nontemporal_store(hold[k],
                                        out_base + (size_t)(T_ - 1) * H_ + k);
    }
}

// ---------------------------------------------------------------------------
extern "C" void kernel_launch(void* const* d_in, const int* in_sizes, int n_in,
                              void* d_out, int out_size, void* d_ws, size_t ws_size,
                              hipStream_t stream) {
    const float* x   = (const float*)d_in[0];
    const float* Wih = (const float*)d_in[1];
    const float* Whh = (const float*)d_in[2];
    const float* bih = (const float*)d_in[3];
    const float* bhh = (const float*)d_in[4];
    float* out = (float*)d_out;
    unsigned* ws = (unsigned*)d_ws;

    // ring=8 needs 4KB flags + 8*64KB; fallback ring=2 fits 132KB.
    const size_t need8 = (size_t)(1024 + 8 * 16384) * sizeof(unsigned);
    const int ring = (ws_size >= need8) ? 8 : 2;

    k_init<<<64, 256, 0, stream>>>(ws, ring);
    k_xp<<<128 * 8, 256, 0, stream>>>(x, Wih, bih, bhh, out);
    k_rnn<<<NWAVE, 128, 0, stream>>>(Whh, out, ws, ring);
}